// Round 1
// baseline (1167.829 us; speedup 1.0000x reference)
//
#include <hip/hip_runtime.h>
#include <hip/hip_fp16.h>

#define B_ 512
#define T_ 512
#define D_ 64
#define H_ 64
#define K_ 4

// ws layout: wh_half [K*3*H*H] @0 (98304 B), wi_half [3*H*H] @98304 (24576 B), flag @122880
#define WS_WI_OFF   98304
#define WS_FLAG_OFF 122880

__device__ __forceinline__ float lanef(float v, int l) {
    return __int_as_float(__builtin_amdgcn_readlane(__float_as_int(v), l));
}

union HU { uint4 u[4]; __half2 h[16]; };

__device__ __forceinline__ float hx(const HU& a, int jj) {
    __half2 v = a.h[jj >> 1];
    return (jj & 1) ? __high2float(v) : __low2float(v);
}

// Detect whether mask buffer is 1-byte bools or int32 0/1 (little-endian).
// If int32, every byte at offset %4 != 0 of the first 1024 values is 0.
__global__ void detect_mask_kernel(const unsigned char* __restrict__ mb, int* __restrict__ flag) {
    __shared__ int cnt;
    if (threadIdx.x == 0) cnt = 0;
    __syncthreads();
    int c = 0;
    for (int i = threadIdx.x; i < 4096; i += blockDim.x)
        if ((i & 3) != 0 && mb[i] != 0) c++;
    atomicAdd(&cnt, c);
    __syncthreads();
    if (threadIdx.x == 0) *flag = (cnt > 0) ? 1 : 0;  // 1 => uint8 bools, 0 => int32
}

// Convert W_h* [K,H,H] -> wh half layout ((k*3+g)*H + i)*H + j ; W_i* [H,H] -> wi (g*H+i)*H+j
__global__ void convert_weights_kernel(const float* __restrict__ Whr, const float* __restrict__ Whz,
                                       const float* __restrict__ Whn, const float* __restrict__ Wir,
                                       const float* __restrict__ Wiz, const float* __restrict__ Win,
                                       __half* __restrict__ wh, __half* __restrict__ wi) {
    int idx = blockIdx.x * 256 + threadIdx.x;
    if (idx < K_ * 3 * H_ * H_) {
        int k = idx / (3 * H_ * H_);
        int r = idx - k * (3 * H_ * H_);
        int g = r >> 12;            // /4096
        int i = (r >> 6) & 63;
        int j = r & 63;
        const float* src = (g == 0) ? Whr : (g == 1) ? Whz : Whn;
        wh[idx] = __float2half(src[(k * H_ + i) * H_ + j]);
    }
    if (idx < 3 * H_ * H_) {
        int g = idx >> 12;
        int i = (idx >> 6) & 63;
        int j = idx & 63;
        const float* src = (g == 0) ? Wir : (g == 1) ? Wiz : Win;
        wi[idx] = __float2half(src[i * H_ + j]);
    }
}

// One block per batch element. 2 waves: wave w handles j in [32w, 32w+32).
// lane = output index i. h kept replicated in lane-registers of both waves.
__global__ __launch_bounds__(128, 1)
void gru_main_kernel(const float* __restrict__ x, const int* __restrict__ ctx,
                     const unsigned char* __restrict__ mask_bytes, const int* __restrict__ flag_p,
                     const __half* __restrict__ wh, const __half* __restrict__ wi,
                     const float* __restrict__ b_ir, const float* __restrict__ b_iz,
                     const float* __restrict__ b_in, const float* __restrict__ b_hr,
                     const float* __restrict__ b_hz, const float* __restrict__ b_hn,
                     const float* __restrict__ Wo_w, const float* __restrict__ Wo_b,
                     float* __restrict__ out) {
    __shared__ float part[6 * 64];
    __shared__ float hbuf[64];

    const int tid  = threadIdx.x;
    const int lane = tid & 63;
    const int wv   = tid >> 6;       // 0 or 1
    const int b    = blockIdx.x;
    const int j0   = wv * 32;

    const int flag   = *flag_p;
    const int mshift = flag ? 0 : 2;  // byte index = idx << mshift (int32 low byte holds 0/1)

    // Input-projection weights: static across t -> registers (f16 packed, 48 VGPRs)
    HU wir_u, wiz_u, win_u;
    {
        const uint4* qr = (const uint4*)(wi + ((0 * H_ + lane) * H_ + j0));
        const uint4* qz = (const uint4*)(wi + ((1 * H_ + lane) * H_ + j0));
        const uint4* qn = (const uint4*)(wi + ((2 * H_ + lane) * H_ + j0));
#pragma unroll
        for (int q = 0; q < 4; q++) { wir_u.u[q] = qr[q]; wiz_u.u[q] = qz[q]; win_u.u[q] = qn[q]; }
    }

    const float bir = b_ir[lane], biz = b_iz[lane], bin = b_in[lane];
    const float wo0 = Wo_w[lane], wo1 = Wo_w[64 + lane];
    const float wob0 = Wo_b[0], wob1 = Wo_b[1];

    float hreg = 0.0f;
    const int base_bt = b * T_;
    float* outp = out + (size_t)b * T_ * 2;

    float xcur = x[(base_bt + 0) * D_ + lane];
    int   kcur = ctx[base_bt + 0];
    float mcur = mask_bytes[(size_t)(base_bt + 0) << mshift] ? 1.0f : 0.0f;

#pragma unroll 1
    for (int t = 0; t < T_; t++) {
        // ---- prefetch next step's x / ctx / mask ----
        const int tn = (t + 1 < T_) ? (t + 1) : t;
        float xnext = x[(base_bt + tn) * D_ + lane];
        int   knext = ctx[base_bt + tn];
        float mnext = mask_bytes[(size_t)(base_bt + tn) << mshift] ? 1.0f : 0.0f;

        // ---- issue W_h row loads (f16 from L2) for this step ----
        const int k = kcur;
        HU whr_u, whz_u, whn_u;
        {
            const uint4* pr = (const uint4*)(wh + (((k * 3 + 0) * H_ + lane) * H_ + j0));
            const uint4* pz = (const uint4*)(wh + (((k * 3 + 1) * H_ + lane) * H_ + j0));
            const uint4* pn = (const uint4*)(wh + (((k * 3 + 2) * H_ + lane) * H_ + j0));
#pragma unroll
            for (int q = 0; q < 4; q++) { whr_u.u[q] = pr[q]; whz_u.u[q] = pz[q]; whn_u.u[q] = pn[q]; }
        }
        const float bhr = b_hr[k * H_ + lane];
        const float bhz = b_hz[k * H_ + lane];
        const float bhn = b_hn[k * H_ + lane];

        // ---- input projections (overlaps W_h load latency) ----
        float s_ir = 0.f, s_iz = 0.f, s_in = 0.f;
#pragma unroll
        for (int jj = 0; jj < 32; jj++) {
            const float xj = lanef(xcur, j0 + jj);
            s_ir = fmaf(hx(wir_u, jj), xj, s_ir);
            s_iz = fmaf(hx(wiz_u, jj), xj, s_iz);
            s_in = fmaf(hx(win_u, jj), xj, s_in);
        }

        // ---- hidden matvecs ----
        float s_hr = 0.f, s_hz = 0.f, s_hn = 0.f;
#pragma unroll
        for (int jj = 0; jj < 32; jj++) {
            const float hj = lanef(hreg, j0 + jj);
            s_hr = fmaf(hx(whr_u, jj), hj, s_hr);
            s_hz = fmaf(hx(whz_u, jj), hj, s_hz);
            s_hn = fmaf(hx(whn_u, jj), hj, s_hn);
        }

        // ---- combine halves ----
        if (wv == 1) {
            part[0 * 64 + lane] = s_ir; part[1 * 64 + lane] = s_iz; part[2 * 64 + lane] = s_in;
            part[3 * 64 + lane] = s_hr; part[4 * 64 + lane] = s_hz; part[5 * 64 + lane] = s_hn;
        }
        __syncthreads();

        if (wv == 0) {
            const float ir  = s_ir + part[0 * 64 + lane] + bir;
            const float iz  = s_iz + part[1 * 64 + lane] + biz;
            const float inn = s_in + part[2 * 64 + lane] + bin;
            const float hr  = s_hr + part[3 * 64 + lane] + bhr;
            const float hz  = s_hz + part[4 * 64 + lane] + bhz;
            const float hn  = s_hn + part[5 * 64 + lane] + bhn;

            const float r = 1.0f / (1.0f + __expf(-(ir + hr)));
            const float z = 1.0f / (1.0f + __expf(-(iz + hz)));
            const float a = inn + r * hn;
            const float n = 2.0f / (1.0f + __expf(-2.0f * a)) - 1.0f;  // tanh, inf-safe
            float hnew = n + z * (hreg - n);
            hnew = (mcur > 0.5f) ? hnew : hreg;
            hbuf[lane] = hnew;

            // logits: reduce h*wo over 64 lanes
            float l0 = hnew * wo0, l1 = hnew * wo1;
#pragma unroll
            for (int m = 32; m >= 1; m >>= 1) {
                l0 += __shfl_xor(l0, m, 64);
                l1 += __shfl_xor(l1, m, 64);
            }
            if (lane == 0) {
                *(float2*)(outp + t * 2) = make_float2(l0 + wob0, l1 + wob1);
            }
        }
        __syncthreads();
        hreg = hbuf[lane];

        xcur = xnext; kcur = knext; mcur = mnext;
    }
}

extern "C" void kernel_launch(void* const* d_in, const int* in_sizes, int n_in,
                              void* d_out, int out_size, void* d_ws, size_t ws_size,
                              hipStream_t stream) {
    const float* x    = (const float*)d_in[0];
    const int*   ctx  = (const int*)d_in[1];
    const void*  mask = d_in[2];
    const float* W_ir = (const float*)d_in[3];
    const float* W_iz = (const float*)d_in[4];
    const float* W_in = (const float*)d_in[5];
    const float* bir  = (const float*)d_in[6];
    const float* biz  = (const float*)d_in[7];
    const float* bin  = (const float*)d_in[8];
    const float* W_hr = (const float*)d_in[9];
    const float* W_hz = (const float*)d_in[10];
    const float* W_hn = (const float*)d_in[11];
    const float* bhr  = (const float*)d_in[12];
    const float* bhz  = (const float*)d_in[13];
    const float* bhn  = (const float*)d_in[14];
    const float* Wo_w = (const float*)d_in[15];
    const float* Wo_b = (const float*)d_in[16];

    char* ws = (char*)d_ws;
    __half* wh  = (__half*)ws;
    __half* wi  = (__half*)(ws + WS_WI_OFF);
    int* flag   = (int*)(ws + WS_FLAG_OFF);

    detect_mask_kernel<<<1, 256, 0, stream>>>((const unsigned char*)mask, flag);
    convert_weights_kernel<<<192, 256, 0, stream>>>(W_hr, W_hz, W_hn, W_ir, W_iz, W_in, wh, wi);
    gru_main_kernel<<<B_, 128, 0, stream>>>(x, ctx, (const unsigned char*)mask, flag,
                                            wh, wi, bir, biz, bin, bhr, bhz, bhn,
                                            Wo_w, Wo_b, (float*)d_out);
}

// Round 2
// 1149.468 us; speedup vs baseline: 1.0160x; 1.0160x over previous
//
#include <hip/hip_runtime.h>
#include <hip/hip_fp16.h>

#define B_ 512
#define T_ 512
#define D_ 64
#define H_ 64
#define K_ 4

// ws layout: wh_half [K*3*H*H] @0 (98304 B), wi_half [3*H*H] @98304 (24576 B), flag @122880
#define WS_WI_OFF   98304
#define WS_FLAG_OFF 122880

__device__ __forceinline__ float lanef(float v, int l) {
    return __int_as_float(__builtin_amdgcn_readlane(__float_as_int(v), l));
}

// 16 halves = 32 B = 2 uint4
union H8 { uint4 u[2]; __half2 h[8]; };

__device__ __forceinline__ float hx(const H8& a, int jj) {
    __half2 v = a.h[jj >> 1];
    return (jj & 1) ? __high2float(v) : __low2float(v);
}

// Detect whether mask buffer is 1-byte bools or int32 0/1 (little-endian).
__global__ void detect_mask_kernel(const unsigned char* __restrict__ mb, int* __restrict__ flag) {
    __shared__ int cnt;
    if (threadIdx.x == 0) cnt = 0;
    __syncthreads();
    int c = 0;
    for (int i = threadIdx.x; i < 4096; i += blockDim.x)
        if ((i & 3) != 0 && mb[i] != 0) c++;
    atomicAdd(&cnt, c);
    __syncthreads();
    if (threadIdx.x == 0) *flag = (cnt > 0) ? 1 : 0;  // 1 => uint8 bools, 0 => int32
}

// Convert W_h* [K,H,H] -> wh half layout ((k*3+g)*H + i)*H + j ; W_i* -> wi (g*H+i)*H+j
__global__ void convert_weights_kernel(const float* __restrict__ Whr, const float* __restrict__ Whz,
                                       const float* __restrict__ Whn, const float* __restrict__ Wir,
                                       const float* __restrict__ Wiz, const float* __restrict__ Win,
                                       __half* __restrict__ wh, __half* __restrict__ wi) {
    int idx = blockIdx.x * 256 + threadIdx.x;
    if (idx < K_ * 3 * H_ * H_) {
        int k = idx / (3 * H_ * H_);
        int r = idx - k * (3 * H_ * H_);
        int g = r >> 12;
        int i = (r >> 6) & 63;
        int j = r & 63;
        const float* src = (g == 0) ? Whr : (g == 1) ? Whz : Whn;
        wh[idx] = __float2half(src[(k * H_ + i) * H_ + j]);
    }
    if (idx < 3 * H_ * H_) {
        int g = idx >> 12;
        int i = (idx >> 6) & 63;
        int j = idx & 63;
        const float* src = (g == 0) ? Wir : (g == 1) ? Wiz : Win;
        wi[idx] = __float2half(src[i * H_ + j]);
    }
}

// One block per batch element. 4 waves; wave w handles j in [16w, 16w+16).
// lane = output index i. Epilogue computed redundantly in ALL waves so each
// wave holds the full h in lane-registers -> one barrier per step, no h
// broadcast round trip.
__global__ __launch_bounds__(256, 2)
void gru_main_kernel(const float* __restrict__ x, const int* __restrict__ ctx,
                     const unsigned char* __restrict__ mask_bytes, const int* __restrict__ flag_p,
                     const __half* __restrict__ wh, const __half* __restrict__ wi,
                     const float* __restrict__ b_ir, const float* __restrict__ b_iz,
                     const float* __restrict__ b_in, const float* __restrict__ b_hr,
                     const float* __restrict__ b_hz, const float* __restrict__ b_hn,
                     const float* __restrict__ Wo_w, const float* __restrict__ Wo_b,
                     float* __restrict__ out) {
    // partials: [buf=2][val=4][wave=4][lane=64]  (val: 0=a_r,1=a_z,2=s_in,3=s_hn)
    __shared__ float part[2 * 4 * 4 * 64];

    const int tid  = threadIdx.x;
    const int lane = tid & 63;
    const int wv   = tid >> 6;       // 0..3
    const int b    = blockIdx.x;
    const int j0   = wv * 16;

    const int flag   = *flag_p;
    const int mshift = flag ? 0 : 2;

    // Input-projection weights for this wave's j-slice: registers (f16)
    H8 wir_u, wiz_u, win_u;
    {
        const uint4* qr = (const uint4*)(wi + ((0 * H_ + lane) * H_ + j0));
        const uint4* qz = (const uint4*)(wi + ((1 * H_ + lane) * H_ + j0));
        const uint4* qn = (const uint4*)(wi + ((2 * H_ + lane) * H_ + j0));
#pragma unroll
        for (int q = 0; q < 2; q++) { wir_u.u[q] = qr[q]; wiz_u.u[q] = qz[q]; win_u.u[q] = qn[q]; }
    }

    const float bir = b_ir[lane], biz = b_iz[lane], bin = b_in[lane];
    const float wo0 = Wo_w[lane], wo1 = Wo_w[64 + lane];
    const float wob0 = Wo_b[0], wob1 = Wo_b[1];

    float hreg = 0.0f;
    const int base_bt = b * T_;
    float* outp = out + (size_t)b * T_ * 2;

    float xcur = x[(base_bt + 0) * D_ + lane];
    int   kcur = ctx[base_bt + 0];
    float mcur = mask_bytes[(size_t)(base_bt + 0) << mshift] ? 1.0f : 0.0f;

#pragma unroll 1
    for (int t = 0; t < T_; t++) {
        // ---- prefetch next step's x / ctx / mask ----
        const int tn = (t + 1 < T_) ? (t + 1) : t;
        float xnext = x[(base_bt + tn) * D_ + lane];
        int   knext = ctx[base_bt + tn];
        float mnext = mask_bytes[(size_t)(base_bt + tn) << mshift] ? 1.0f : 0.0f;

        // ---- issue W_h slice loads (f16 from L2) + biases for this step ----
        const int k = kcur;
        H8 whr_u, whz_u, whn_u;
        {
            const uint4* pr = (const uint4*)(wh + (((k * 3 + 0) * H_ + lane) * H_ + j0));
            const uint4* pz = (const uint4*)(wh + (((k * 3 + 1) * H_ + lane) * H_ + j0));
            const uint4* pn = (const uint4*)(wh + (((k * 3 + 2) * H_ + lane) * H_ + j0));
#pragma unroll
            for (int q = 0; q < 2; q++) { whr_u.u[q] = pr[q]; whz_u.u[q] = pz[q]; whn_u.u[q] = pn[q]; }
        }
        const float bhr = b_hr[k * H_ + lane];
        const float bhz = b_hz[k * H_ + lane];
        const float bhn = b_hn[k * H_ + lane];

        // ---- input projections (overlaps W_h load latency) ----
        float s_ir = 0.f, s_iz = 0.f, s_in = 0.f;
#pragma unroll
        for (int jj = 0; jj < 16; jj++) {
            const float xj = lanef(xcur, j0 + jj);
            s_ir = fmaf(hx(wir_u, jj), xj, s_ir);
            s_iz = fmaf(hx(wiz_u, jj), xj, s_iz);
            s_in = fmaf(hx(win_u, jj), xj, s_in);
        }

        // ---- hidden matvecs ----
        float s_hr = 0.f, s_hz = 0.f, s_hn = 0.f;
#pragma unroll
        for (int jj = 0; jj < 16; jj++) {
            const float hj = lanef(hreg, j0 + jj);
            s_hr = fmaf(hx(whr_u, jj), hj, s_hr);
            s_hz = fmaf(hx(whz_u, jj), hj, s_hz);
            s_hn = fmaf(hx(whn_u, jj), hj, s_hn);
        }

        // ---- write partials (r/z pre-summed), one barrier ----
        float* buf = part + (t & 1) * 1024;
        buf[0 * 256 + wv * 64 + lane] = s_ir + s_hr;
        buf[1 * 256 + wv * 64 + lane] = s_iz + s_hz;
        buf[2 * 256 + wv * 64 + lane] = s_in;
        buf[3 * 256 + wv * 64 + lane] = s_hn;
        __syncthreads();

        // ---- redundant epilogue in every wave ----
        float ar = 0.f, az = 0.f, sn = 0.f, shn = 0.f;
#pragma unroll
        for (int w = 0; w < 4; w++) {
            ar  += buf[0 * 256 + w * 64 + lane];
            az  += buf[1 * 256 + w * 64 + lane];
            sn  += buf[2 * 256 + w * 64 + lane];
            shn += buf[3 * 256 + w * 64 + lane];
        }
        const float r = 1.0f / (1.0f + __expf(-(ar + bir + bhr)));
        const float z = 1.0f / (1.0f + __expf(-(az + biz + bhz)));
        const float a = sn + bin + r * (shn + bhn);
        const float n = 2.0f / (1.0f + __expf(-2.0f * a)) - 1.0f;  // tanh, inf-safe
        float hnew = n + z * (hreg - n);
        hnew = (mcur > 0.5f) ? hnew : hreg;
        hreg = hnew;

        // ---- logits (wave0 only) ----
        if (wv == 0) {
            float l0 = hnew * wo0, l1 = hnew * wo1;
#pragma unroll
            for (int m = 32; m >= 1; m >>= 1) {
                l0 += __shfl_xor(l0, m, 64);
                l1 += __shfl_xor(l1, m, 64);
            }
            if (lane == 0) {
                *(float2*)(outp + t * 2) = make_float2(l0 + wob0, l1 + wob1);
            }
        }

        xcur = xnext; kcur = knext; mcur = mnext;
    }
}

extern "C" void kernel_launch(void* const* d_in, const int* in_sizes, int n_in,
                              void* d_out, int out_size, void* d_ws, size_t ws_size,
                              hipStream_t stream) {
    const float* x    = (const float*)d_in[0];
    const int*   ctx  = (const int*)d_in[1];
    const void*  mask = d_in[2];
    const float* W_ir = (const float*)d_in[3];
    const float* W_iz = (const float*)d_in[4];
    const float* W_in = (const float*)d_in[5];
    const float* bir  = (const float*)d_in[6];
    const float* biz  = (const float*)d_in[7];
    const float* bin  = (const float*)d_in[8];
    const float* W_hr = (const float*)d_in[9];
    const float* W_hz = (const float*)d_in[10];
    const float* W_hn = (const float*)d_in[11];
    const float* bhr  = (const float*)d_in[12];
    const float* bhz  = (const float*)d_in[13];
    const float* bhn  = (const float*)d_in[14];
    const float* Wo_w = (const float*)d_in[15];
    const float* Wo_b = (const float*)d_in[16];

    char* ws = (char*)d_ws;
    __half* wh  = (__half*)ws;
    __half* wi  = (__half*)(ws + WS_WI_OFF);
    int* flag   = (int*)(ws + WS_FLAG_OFF);

    detect_mask_kernel<<<1, 256, 0, stream>>>((const unsigned char*)mask, flag);
    convert_weights_kernel<<<192, 256, 0, stream>>>(W_hr, W_hz, W_hn, W_ir, W_iz, W_in, wh, wi);
    gru_main_kernel<<<B_, 256, 0, stream>>>(x, ctx, (const unsigned char*)mask, flag,
                                            wh, wi, bir, biz, bin, bhr, bhz, bhn,
                                            Wo_w, Wo_b, (float*)d_out);
}

// Round 5
// 749.589 us; speedup vs baseline: 1.5580x; 1.5335x over previous
//
#include <hip/hip_runtime.h>
#include <hip/hip_fp16.h>

#define B_ 512
#define T_ 512
#define H_ 64
#define K_ 4

// ws layout: wh_half [K*3*H*H] @0 (98304 B), wi_half [3*H*H] @98304 (24576 B), flag @122880
#define WS_WI_OFF   98304
#define WS_FLAG_OFF 122880

typedef _Float16 half2_t __attribute__((ext_vector_type(2)));

union Q { uint4 u; half2_t h[4]; };  // 16 B = 4 packed half2

__device__ __forceinline__ float fdot2f(half2_t a, half2_t b, float c) {
#if __has_builtin(__builtin_amdgcn_fdot2)
    return __builtin_amdgcn_fdot2(a, b, c, false);
#else
    return fmaf((float)a[0], (float)b[0], fmaf((float)a[1], (float)b[1], c));
#endif
}

// v_cvt_pkrtz_f16_f32 returns <2 x __fp16>; bit-cast to our half2_t.
__device__ __forceinline__ half2_t pkh2(float a, float b) {
    return __builtin_bit_cast(half2_t, __builtin_amdgcn_cvt_pkrtz(a, b));
}

// Detect whether mask buffer is 1-byte bools or int32 0/1 (little-endian).
__global__ void detect_mask_kernel(const unsigned char* __restrict__ mb, int* __restrict__ flag) {
    __shared__ int cnt;
    if (threadIdx.x == 0) cnt = 0;
    __syncthreads();
    int c = 0;
    for (int i = threadIdx.x; i < 4096; i += blockDim.x)
        if ((i & 3) != 0 && mb[i] != 0) c++;
    atomicAdd(&cnt, c);
    __syncthreads();
    if (threadIdx.x == 0) *flag = (cnt > 0) ? 1 : 0;  // 1 => uint8 bools, 0 => int32
}

// W_h* [K,H,H] -> wh f16, layout ((k*3+g)*H + i)*H + j ; W_i* -> wi (g*H+i)*H+j
__global__ void convert_weights_kernel(const float* __restrict__ Whr, const float* __restrict__ Whz,
                                       const float* __restrict__ Whn, const float* __restrict__ Wir,
                                       const float* __restrict__ Wiz, const float* __restrict__ Win,
                                       __half* __restrict__ wh, __half* __restrict__ wi) {
    int idx = blockIdx.x * 256 + threadIdx.x;
    if (idx < K_ * 3 * H_ * H_) {
        int k = idx / (3 * H_ * H_);
        int r = idx - k * (3 * H_ * H_);
        int g = r >> 12;
        int i = (r >> 6) & 63;
        int j = r & 63;
        const float* src = (g == 0) ? Whr : (g == 1) ? Whz : Whn;
        wh[idx] = __float2half(src[(k * H_ + i) * H_ + j]);
    }
    if (idx < 3 * H_ * H_) {
        int g = idx >> 12;
        int i = (idx >> 6) & 63;
        int j = idx & 63;
        const float* src = (g == 0) ? Wir : (g == 1) ? Wiz : Win;
        wi[idx] = __float2half(src[i * H_ + j]);
    }
}

// One block per batch element. 4 waves; wave wv == expert wv.
// Each wave holds expert wv's full W_h (3 gates x 64x64 f16) in 96 VGPRs.
// Per step only the wave matching k_t computes the hidden matvec (packed-f16
// h via v_dot2). Input proj is j-split 4-way across waves. lane = output i.
//
// Correctness-hardened structure:
//  - h has a SINGLE source of truth: wave 0 computes the epilogue, persists
//    h to LDS (f32 + f16-packed); ALL waves re-read it every step. No
//    replicated state that can diverge persistently.
//  - ALL LDS arrays double-buffered (written at t, read at t, rewritten at
//    t+2: >=2 barriers between any read and the next write).
__global__ __launch_bounds__(256, 2)
void gru_main_kernel(const float* __restrict__ x, const int* __restrict__ ctx,
                     const unsigned char* __restrict__ mask_bytes, const int* __restrict__ flag_p,
                     const __half* __restrict__ wh, const __half* __restrict__ wi,
                     const float* __restrict__ b_ir, const float* __restrict__ b_iz,
                     const float* __restrict__ b_in, const float* __restrict__ b_hr,
                     const float* __restrict__ b_hz, const float* __restrict__ b_hn,
                     const float* __restrict__ Wo_w, const float* __restrict__ Wo_b,
                     float* __restrict__ out) {
    __shared__ float4 slots[2][4][64];             // [buf][wave][lane]: (ar, az, s_in, s_hn)
    __shared__ __align__(16) __half hpk[2][64];    // packed-f16 h, written by wave0
    __shared__ float hf32[2][64];                  // f32 h, written by wave0

    const int tid  = threadIdx.x;
    const int lane = tid & 63;
    const int wv   = tid >> 6;     // 0..3 == expert id
    const int b    = blockIdx.x;

    const int flag   = *flag_p;
    const int mshift = flag ? 0 : 2;

    // ---- expert wv's hidden weights: full rows, 96 VGPRs ----
    Q whr[8], whz[8], whn[8];
    {
        const uint4* pr = (const uint4*)(wh + ((size_t)((wv * 3 + 0) * H_ + lane) * H_));
        const uint4* pz = (const uint4*)(wh + ((size_t)((wv * 3 + 1) * H_ + lane) * H_));
        const uint4* pn = (const uint4*)(wh + ((size_t)((wv * 3 + 2) * H_ + lane) * H_));
#pragma unroll
        for (int q = 0; q < 8; q++) { whr[q].u = pr[q]; whz[q].u = pz[q]; whn[q].u = pn[q]; }
    }
    // ---- input weights, this wave's j-quarter [16*wv, 16*wv+16) ----
    Q wir[2], wiz[2], win[2];
    {
        const uint4* qr = (const uint4*)(wi + ((0 * H_ + lane) * H_ + wv * 16));
        const uint4* qz = (const uint4*)(wi + ((1 * H_ + lane) * H_ + wv * 16));
        const uint4* qn = (const uint4*)(wi + ((2 * H_ + lane) * H_ + wv * 16));
#pragma unroll
        for (int q = 0; q < 2; q++) { wir[q].u = qr[q]; wiz[q].u = qz[q]; win[q].u = qn[q]; }
    }

    // epilogue constants (used by wave 0 only; loads are loop-invariant)
    const float bir = b_ir[lane], biz = b_iz[lane], bin = b_in[lane];
    const float wo0 = Wo_w[lane], wo1 = Wo_w[64 + lane];
    const float wob0 = Wo_b[0], wob1 = Wo_b[1];

    float hreg = 0.0f;   // wave0's f32 h carry (re-read from LDS every step)
    Q hq[8];             // packed h for matvec (re-read from LDS every step)
#pragma unroll
    for (int q = 0; q < 8; q++) hq[q].u = make_uint4(0u, 0u, 0u, 0u);

    const int base_bt = b * T_;
    float* outp = out + (size_t)b * T_ * 2;

    // current-step inputs (t = 0)
    float4 xc0, xc1, xc2, xc3;
    {
        const float4* xr = (const float4*)(x + (size_t)base_bt * H_) + wv * 4;
        xc0 = xr[0]; xc1 = xr[1]; xc2 = xr[2]; xc3 = xr[3];
    }
    int   kcur = __builtin_amdgcn_readfirstlane(ctx[base_bt]);
    float mcur = mask_bytes[(size_t)base_bt << mshift] ? 1.0f : 0.0f;

#pragma unroll 1
    for (int t = 0; t < T_; t++) {
        const int p = t & 1;

        // ---- prefetch next step ----
        const int tn = (t + 1 < T_) ? (t + 1) : t;
        const float4* xr = (const float4*)(x + (size_t)(base_bt + tn) * H_) + wv * 4;
        float4 xn0 = xr[0], xn1 = xr[1], xn2 = xr[2], xn3 = xr[3];
        int   knext = ctx[base_bt + tn];
        float mnext = mask_bytes[(size_t)(base_bt + tn) << mshift] ? 1.0f : 0.0f;

        // ---- pack x quarter to half2 ----
        half2_t xh[8];
        xh[0] = pkh2(xc0.x, xc0.y);
        xh[1] = pkh2(xc0.z, xc0.w);
        xh[2] = pkh2(xc1.x, xc1.y);
        xh[3] = pkh2(xc1.z, xc1.w);
        xh[4] = pkh2(xc2.x, xc2.y);
        xh[5] = pkh2(xc2.z, xc2.w);
        xh[6] = pkh2(xc3.x, xc3.y);
        xh[7] = pkh2(xc3.z, xc3.w);

        // ---- input proj over this wave's j-quarter (24 fdot2) ----
        float sir = 0.f, siz = 0.f, sin_ = 0.f;
#pragma unroll
        for (int q = 0; q < 2; q++)
#pragma unroll
            for (int pp = 0; pp < 4; pp++) {
                const int m = q * 4 + pp;
                sir  = fdot2f(wir[q].h[pp], xh[m], sir);
                siz  = fdot2f(wiz[q].h[pp], xh[m], siz);
                sin_ = fdot2f(win[q].h[pp], xh[m], sin_);
            }

        // ---- hidden matvec: matching expert wave only (96 fdot2, full j) ----
        float shr = 0.f, shz = 0.f, shn = 0.f;
        if (kcur == wv) {
#pragma unroll
            for (int q = 0; q < 8; q++)
#pragma unroll
                for (int pp = 0; pp < 4; pp++) {
                    shr = fdot2f(whr[q].h[pp], hq[q].h[pp], shr);
                    shz = fdot2f(whz[q].h[pp], hq[q].h[pp], shz);
                    shn = fdot2f(whn[q].h[pp], hq[q].h[pp], shn);
                }
        }

        slots[p][wv][lane] = make_float4(sir + shr, siz + shz, sin_, shn);
        __syncthreads();   // barrier A

        // ---- epilogue: wave 0 ONLY (single source of truth for h) ----
        if (wv == 0) {
            const float4 s0 = slots[p][0][lane];
            const float4 s1 = slots[p][1][lane];
            const float4 s2 = slots[p][2][lane];
            const float4 s3 = slots[p][3][lane];
            const float bhr = b_hr[kcur * H_ + lane];
            const float bhz = b_hz[kcur * H_ + lane];
            const float bhn = b_hn[kcur * H_ + lane];
            const float ar = s0.x + s1.x + s2.x + s3.x + bir + bhr;
            const float az = s0.y + s1.y + s2.y + s3.y + biz + bhz;
            const float an = s0.z + s1.z + s2.z + s3.z + bin;
            const float ah = s0.w + s1.w + s2.w + s3.w + bhn;

            const float r = 1.0f / (1.0f + __expf(-ar));
            const float z = 1.0f / (1.0f + __expf(-az));
            const float a = an + r * ah;
            const float n = 2.0f / (1.0f + __expf(-2.0f * a)) - 1.0f;  // tanh, inf-safe
            float hnew = n + z * (hreg - n);
            hnew = (mcur > 0.5f) ? hnew : hreg;

            hpk[p][lane]  = __float2half(hnew);
            hf32[p][lane] = hnew;

            // logits from the persisted value
            float l0 = hnew * wo0, l1 = hnew * wo1;
#pragma unroll
            for (int m = 32; m >= 1; m >>= 1) {
                l0 += __shfl_xor(l0, m, 64);
                l1 += __shfl_xor(l1, m, 64);
            }
            if (lane == 0) {
                *(float2*)(outp + t * 2) = make_float2(l0 + wob0, l1 + wob1);
            }
        }
        __syncthreads();   // barrier B

        // ---- ALL waves refresh h state from LDS (single source of truth) ----
        hreg = hf32[p][lane];
        {
            const uint4* hp = (const uint4*)hpk[p];
#pragma unroll
            for (int q = 0; q < 8; q++) hq[q].u = hp[q];
        }

        xc0 = xn0; xc1 = xn1; xc2 = xn2; xc3 = xn3;
        kcur = __builtin_amdgcn_readfirstlane(knext);
        mcur = mnext;
    }
}

extern "C" void kernel_launch(void* const* d_in, const int* in_sizes, int n_in,
                              void* d_out, int out_size, void* d_ws, size_t ws_size,
                              hipStream_t stream) {
    const float* x    = (const float*)d_in[0];
    const int*   ctx  = (const int*)d_in[1];
    const void*  mask = d_in[2];
    const float* W_ir = (const float*)d_in[3];
    const float* W_iz = (const float*)d_in[4];
    const float* W_in = (const float*)d_in[5];
    const float* bir  = (const float*)d_in[6];
    const float* biz  = (const float*)d_in[7];
    const float* bin  = (const float*)d_in[8];
    const float* W_hr = (const float*)d_in[9];
    const float* W_hz = (const float*)d_in[10];
    const float* W_hn = (const float*)d_in[11];
    const float* bhr  = (const float*)d_in[12];
    const float* bhz  = (const float*)d_in[13];
    const float* bhn  = (const float*)d_in[14];
    const float* Wo_w = (const float*)d_in[15];
    const float* Wo_b = (const float*)d_in[16];

    char* ws = (char*)d_ws;
    __half* wh  = (__half*)ws;
    __half* wi  = (__half*)(ws + WS_WI_OFF);
    int* flag   = (int*)(ws + WS_FLAG_OFF);

    detect_mask_kernel<<<1, 256, 0, stream>>>((const unsigned char*)mask, flag);
    convert_weights_kernel<<<192, 256, 0, stream>>>(W_hr, W_hz, W_hn, W_ir, W_iz, W_in, wh, wi);
    gru_main_kernel<<<B_, 256, 0, stream>>>(x, ctx, (const unsigned char*)mask, flag,
                                            wh, wi, bir, biz, bin, bhr, bhz, bhn,
                                            Wo_w, Wo_b, (float*)d_out);
}